// Round 1
// baseline (1076.686 us; speedup 1.0000x reference)
//
#include <hip/hip_runtime.h>

#define TSTEPS 128
#define NFEAT 16

__device__ __forceinline__ float shflx(float v, int mask) {
    return __shfl_xor(v, mask, 64);
}
__device__ __forceinline__ float rdlane(float v, int l) {
    return __uint_as_float(__builtin_amdgcn_readlane(__float_as_uint(v), l));
}
__device__ __forceinline__ float frcp(float x) { return __builtin_amdgcn_rcpf(x); }
__device__ __forceinline__ float frsq(float x) { return __builtin_amdgcn_rsqf(x); }
__device__ __forceinline__ float fsqrt_(float x) { return __builtin_amdgcn_sqrtf(x); }

__device__ __forceinline__ float sigm(float x) { return frcp(1.f + __expf(-x)); }
// tanh(x) = 1 - 2/(e^{2x}+1)  (stable both directions; inf -> 1, 0 -> -1)
__device__ __forceinline__ float tanh_f(float x) { return 1.f - 2.f * frcp(__expf(2.f * x) + 1.f); }

// c = cos(atan(u)/2), s = sin(atan(u)/2) via exact half-angle algebra:
// cos(atan u) = rsqrt(1+u^2); c = sqrt((1+cos)/2); s = sin/(2c), sin = u*cos.
__device__ __forceinline__ void half_cs(float u, float &c, float &s) {
    float ca = frsq(1.f + u * u);
    c = fsqrt_((1.f + ca) * 0.5f);
    s = u * ca * 0.5f * frcp(c);
}

// One 4-wire circuit for this lane's 16-lane group. Lane bit q <-> wire q.
// Input: per-wire init factors (bit? (s1*c2, s1*s2) : (c1*c2, -c1*s2)) built
// from c1/s1 (RY half-angle) and c2/s2 (RZ half-angle); g = LDS cos/sin table
// for this circuit's phi rotations (48 floats). Returns the per-lane WHT of
// probabilities: lane (1<<q) holds <Z_q>.
__device__ __forceinline__ float circuit(const float c1[4], const float s1[4],
                                         const float c2[4], const float s2[4],
                                         const float* __restrict__ g, int m) {
    float re, im;
    {   // tensor-product initial state (RY then RZ applied to |0>)
        bool b = m & 1;
        float tr = b ? s1[0] : c1[0];
        float ti = b ? s1[0] : -c1[0];
        re = tr * c2[0];
        im = ti * s2[0];
    }
    #pragma unroll
    for (int q = 1; q < 4; ++q) {
        bool b = (m >> q) & 1;
        float tr = b ? s1[q] : c1[q];
        float ti = b ? s1[q] : -c1[q];
        float fre = tr * c2[q], fim = ti * s2[q];
        float nre = re * fre - im * fim;
        float nim = re * fim + im * fre;
        re = nre; im = nim;
    }
    #pragma unroll
    for (int l = 0; l < 2; ++l) {
        // CNOT rings: (i, i+1) then (i, i+2), applied in reference order
        #pragma unroll
        for (int r = 0; r < 2; ++r) {
            int d = r + 1;
            #pragma unroll
            for (int i = 0; i < 4; ++i) {
                int tb = (i + d) & 3;
                float pre = shflx(re, 1 << tb);
                float pim = shflx(im, 1 << tb);
                bool bc = (m >> i) & 1;
                re = bc ? pre : re;
                im = bc ? pim : im;
            }
        }
        // per-wire RX, RY, RZ with phi-derived (cos,sin) from LDS
        #pragma unroll
        for (int i = 0; i < 4; ++i) {
            bool bi = (m >> i) & 1;
            const float* gp = g + (l * 12 + 3 * i) * 2;
            {   // RX: re' = c*re + s*pim ; im' = c*im - s*pre
                float cg = gp[0], sg = gp[1];
                float pre = shflx(re, 1 << i);
                float pim = shflx(im, 1 << i);
                float nre = cg * re + sg * pim;
                float nim = cg * im - sg * pre;
                re = nre; im = nim;
            }
            {   // RY: B = bit? s : -s ; amp' = c*amp + B*partner
                float cg = gp[2], sg = gp[3];
                float pre = shflx(re, 1 << i);
                float pim = shflx(im, 1 << i);
                float bs = bi ? sg : -sg;
                re = cg * re + bs * pre;
                im = cg * im + bs * pim;
            }
            {   // RZ: multiply by (c, bit? +s : -s)
                float cg = gp[4], sg = gp[5];
                float ss = bi ? sg : -sg;
                float nre = cg * re - ss * im;
                float nim = cg * im + ss * re;
                re = nre; im = nim;
            }
        }
    }
    // Walsh-Hadamard of probabilities over the 16-lane group:
    // after 4 stages lane m holds sum_s (-1)^{popcount(m&s)} p_s.
    float p = re * re + im * im;
    #pragma unroll
    for (int st = 1; st <= 8; st <<= 1) {
        float o = shflx(p, st);
        p = ((m & st) ? (o - p) : (o + p));
    }
    return p;
}

__global__ void __launch_bounds__(256) qlstm_kernel(
    const float* __restrict__ x, const float* __restrict__ phi,
    const float* __restrict__ Wd, const float* __restrict__ bd,
    float* __restrict__ out, int B)
{
    __shared__ float gtab[288];   // (circuit k, layer l, wire i, gate g) -> (cos, sin) of angle/2
    for (int i = threadIdx.x; i < 144; i += 256) {
        float a = 0.5f * phi[i];
        gtab[2 * i] = cosf(a);
        gtab[2 * i + 1] = sinf(a);
    }
    __syncthreads();

    const int lane = threadIdx.x & 63;
    const int b = blockIdx.x * 4 + (threadIdx.x >> 6);   // wave = batch element
    const int m = lane & 15;                              // state index within group
    const int grp = lane >> 4;                            // circuit group 0..3
    const float* g1 = gtab + grp * 48;                    // phase 1: phi[grp]
    const float* g2 = gtab + (4 + (grp & 1)) * 48;        // phase 2: phi[4] (g0,2) / phi[5] (g1,3)

    // hoisted Wd rows: lane m contributes x_m*Wd[m,0..3] (+ h_m*Wd[16+m,0..3] for m<4)
    float wA0 = Wd[m * 20 + 0], wA1 = Wd[m * 20 + 1], wA2 = Wd[m * 20 + 2], wA3 = Wd[m * 20 + 3];
    float wB0 = 0.f, wB1 = 0.f, wB2 = 0.f, wB3 = 0.f;
    if (m < 4) {
        wB0 = Wd[(16 + m) * 20 + 0]; wB1 = Wd[(16 + m) * 20 + 1];
        wB2 = Wd[(16 + m) * 20 + 2]; wB3 = Wd[(16 + m) * 20 + 3];
    }
    const float bd0 = bd[0], bd1 = bd[1], bd2 = bd[2], bd3 = bd[3];

    float h0 = 0.f, h1 = 0.f, h2 = 0.f, h3 = 0.f;
    float cc0 = 0.f, cc1 = 0.f, cc2 = 0.f, cc3 = 0.f;

    const float* xp = x + (size_t)b * TSTEPS * NFEAT;
    float* yp = out + (size_t)b * TSTEPS * 4;

    float xv = xp[m];   // prefetched x[b,t,m]
    for (int t = 0; t < TSTEPS; ++t) {
        // z_j = bd_j + sum_k x_k Wd[k,j] + sum_q h_q Wd[16+q,j], j=0..3 (only 4 cols needed!)
        float hsel = (m == 0) ? h0 : (m == 1) ? h1 : (m == 2) ? h2 : h3;
        float p0 = xv * wA0 + hsel * wB0;
        float p1 = xv * wA1 + hsel * wB1;
        float p2 = xv * wA2 + hsel * wB2;
        float p3 = xv * wA3 + hsel * wB3;
        #pragma unroll
        for (int st = 1; st <= 8; st <<= 1) {
            p0 += shflx(p0, st);
            p1 += shflx(p1, st);
            p2 += shflx(p2, st);
            p3 += shflx(p3, st);
        }
        if (t + 1 < TSTEPS) xv = xp[(t + 1) * NFEAT + m];   // prefetch next step

        float c1[4], s1[4], c2[4], s2[4];
        {
            float zz[4] = {p0 + bd0, p1 + bd1, p2 + bd2, p3 + bd3};
            #pragma unroll
            for (int q = 0; q < 4; ++q) {
                // Xf = 2*sigmoid(z)-1 = (e^z-1)/(e^z+1)
                float u = 1.f - 2.f * frcp(__expf(zz[q]) + 1.f);
                half_cs(u, c1[q], s1[q]);         // RY(atan(u))
                half_cs(u * u, c2[q], s2[q]);     // RZ(atan(u^2))
            }
        }
        float w1 = circuit(c1, s1, c2, s2, g1, m);

        // gather f,i,Cg,o expectations from the four groups (lane 16g + 2^q)
        float fv0 = sigm(rdlane(w1, 1)),  fv1 = sigm(rdlane(w1, 2)),  fv2 = sigm(rdlane(w1, 4)),  fv3 = sigm(rdlane(w1, 8));
        float iv0 = sigm(rdlane(w1, 17)), iv1 = sigm(rdlane(w1, 18)), iv2 = sigm(rdlane(w1, 20)), iv3 = sigm(rdlane(w1, 24));
        float Cv0 = sigm(rdlane(w1, 33)), Cv1 = sigm(rdlane(w1, 34)), Cv2 = sigm(rdlane(w1, 36)), Cv3 = sigm(rdlane(w1, 40));
        float ov0 = sigm(rdlane(w1, 49)), ov1 = sigm(rdlane(w1, 50)), ov2 = sigm(rdlane(w1, 52)), ov3 = sigm(rdlane(w1, 56));

        cc0 = fv0 * cc0 + iv0 * Cv0;
        cc1 = fv1 * cc1 + iv1 * Cv1;
        cc2 = fv2 * cc2 + iv2 * Cv2;
        cc3 = fv3 * cc3 + iv3 * Cv3;
        float rs[4] = {ov0 * tanh_f(cc0), ov1 * tanh_f(cc1), ov2 * tanh_f(cc2), ov3 * tanh_f(cc3)};
        #pragma unroll
        for (int q = 0; q < 4; ++q) {
            half_cs(rs[q], c1[q], s1[q]);
            half_cs(rs[q] * rs[q], c2[q], s2[q]);
        }
        float w2 = circuit(c1, s1, c2, s2, g2, m);

        h0 = rdlane(w2, 1);  h1 = rdlane(w2, 2);  h2 = rdlane(w2, 4);  h3 = rdlane(w2, 8);   // phi[4] (group 0)
        float y0 = rdlane(w2, 17), y1 = rdlane(w2, 18), y2 = rdlane(w2, 20), y3 = rdlane(w2, 24); // phi[5] (group 1)
        if (lane < 4) {
            float yv = (lane == 0) ? y0 : (lane == 1) ? y1 : (lane == 2) ? y2 : y3;
            yp[t * 4 + lane] = yv;
        }
    }
    if (lane < 4) {
        float* cp = out + (size_t)B * TSTEPS * 4 + (size_t)b * 4;
        float* hp = out + (size_t)B * TSTEPS * 4 + (size_t)B * 4 + (size_t)b * 4;
        float cv = (lane == 0) ? cc0 : (lane == 1) ? cc1 : (lane == 2) ? cc2 : cc3;
        float hv = (lane == 0) ? h0 : (lane == 1) ? h1 : (lane == 2) ? h2 : h3;
        cp[lane] = cv;
        hp[lane] = hv;
    }
}

extern "C" void kernel_launch(void* const* d_in, const int* in_sizes, int n_in,
                              void* d_out, int out_size, void* d_ws, size_t ws_size,
                              hipStream_t stream) {
    const float* x   = (const float*)d_in[0];
    const float* phi = (const float*)d_in[1];
    const float* Wd  = (const float*)d_in[2];
    const float* bd  = (const float*)d_in[3];
    float* out = (float*)d_out;
    int B = in_sizes[0] / (TSTEPS * NFEAT);   // 4096
    int blocks = (B + 3) / 4;                 // 4 batch elements (waves) per 256-thread block
    hipLaunchKernelGGL(qlstm_kernel, dim3(blocks), dim3(256), 0, stream,
                       x, phi, Wd, bd, out, B);
}

// Round 2
// 474.426 us; speedup vs baseline: 2.2694x; 2.2694x over previous
//
#include <hip/hip_runtime.h>
#include <math.h>

#define TSTEPS 128
#define NFEAT 16

__device__ __forceinline__ float frcp(float x){ return __builtin_amdgcn_rcpf(x); }
__device__ __forceinline__ float frsq(float x){ return __builtin_amdgcn_rsqf(x); }
__device__ __forceinline__ float fsqrt_(float x){ return __builtin_amdgcn_sqrtf(x); }
__device__ __forceinline__ float rdlane(float v, int l){
    return __uint_as_float(__builtin_amdgcn_readlane(__float_as_uint(v), l));
}

__device__ __forceinline__ float sigm(float x){ return frcp(1.f + __expf(-x)); }
// tanh(x) = 1 - 2/(e^{2x}+1)
__device__ __forceinline__ float tanh_f(float x){ return 1.f - 2.f * frcp(__expf(2.f*x) + 1.f); }

// c = cos(atan(u)/2), s = sin(atan(u)/2); sqrt and rsq of same arg run in parallel
__device__ __forceinline__ void half_cs(float u, float &c, float &s){
    float ca = frsq(1.f + u*u);
    float x = (1.f + ca) * 0.5f;
    c = fsqrt_(x);
    s = u * ca * 0.5f * frsq(x);
}

// cross-lane xor within 16-lane groups: masks 1,2 via DPP quad_perm (VALU pipe),
// masks 4,8 via ds_swizzle BitMode (LDS pipe, no address VGPR)
__device__ __forceinline__ float dpp_xor1(float v){
    return __int_as_float(__builtin_amdgcn_update_dpp(0, __float_as_int(v), 0xB1, 0xF, 0xF, true));
}
__device__ __forceinline__ float dpp_xor2(float v){
    return __int_as_float(__builtin_amdgcn_update_dpp(0, __float_as_int(v), 0x4E, 0xF, 0xF, true));
}
__device__ __forceinline__ float swz_xor4(float v){
    return __int_as_float(__builtin_amdgcn_ds_swizzle(__float_as_int(v), 0x101F));
}
__device__ __forceinline__ float swz_xor8(float v){
    return __int_as_float(__builtin_amdgcn_ds_swizzle(__float_as_int(v), 0x201F));
}
template<int MASK> __device__ __forceinline__ float pshfl(float v){
    if constexpr (MASK == 1) return dpp_xor1(v);
    else if constexpr (MASK == 2) return dpp_xor2(v);
    else if constexpr (MASK == 4) return swz_xor4(v);
    else return swz_xor8(v);
}

template<int I, int D>
__device__ __forceinline__ void cnot_step(float &re, float &im, int m){
    constexpr int TB = (I + D) & 3;
    float pre = pshfl<(1 << TB)>(re);
    float pim = pshfl<(1 << TB)>(im);
    bool bc = (m >> I) & 1;
    re = bc ? pre : re;
    im = bc ? pim : im;
}

// merged RZ*RY*RX gate on wire I; coeffs {Ar,Ai,Br,Bi} from LDS (per-lane addr ai)
template<int I>
__device__ __forceinline__ void gate_step(float &re, float &im,
                                          const float* __restrict__ gt, int ai, int loff){
    const float4 g = *(const float4*)((const char*)gt + ai + loff);
    float pre = pshfl<(1 << I)>(re);
    float pim = pshfl<(1 << I)>(im);
    float nre = g.x*re - g.y*im + g.z*pre - g.w*pim;
    float nim = g.x*im + g.y*re + g.z*pim + g.w*pre;
    re = nre; im = nim;
}

// 2 layers of [CNOT ring d=1, ring d=2, merged 1q gates], then WHT of probs.
__device__ __forceinline__ float circuit(float re, float im,
                                         const float* __restrict__ gt,
                                         int a0, int a1, int a2, int a3, int m){
    #pragma unroll
    for (int l = 0; l < 2; ++l){
        const int loff = l * 64;
        cnot_step<0,1>(re, im, m); cnot_step<1,1>(re, im, m);
        cnot_step<2,1>(re, im, m); cnot_step<3,1>(re, im, m);
        cnot_step<0,2>(re, im, m); cnot_step<1,2>(re, im, m);
        cnot_step<2,2>(re, im, m); cnot_step<3,2>(re, im, m);
        gate_step<0>(re, im, gt, a0, loff);
        gate_step<1>(re, im, gt, a1, loff);
        gate_step<2>(re, im, gt, a2, loff);
        gate_step<3>(re, im, gt, a3, loff);
    }
    float p = re*re + im*im;
    { float o = pshfl<1>(p); p = (m & 1) ? o - p : o + p; }
    { float o = pshfl<2>(p); p = (m & 2) ? o - p : o + p; }
    { float o = pshfl<4>(p); p = (m & 4) ? o - p : o + p; }
    { float o = pshfl<8>(p); p = (m & 8) ? o - p : o + p; }
    return p;   // lane 1<<q holds <Z_q>
}

// broadcast packed half-angle values from lanes 0..3 and build the tensor-product
// initial state (RY(a1) then RZ(a2) on |0>): lane m's amplitude.
__device__ __forceinline__ void build_init(float cA, float sA, float cB, float sB,
                                           int m, float &re, float &im){
    float c1v[4], s1v[4], c2v[4], s2v[4];
    #pragma unroll
    for (int q = 0; q < 4; ++q){
        c1v[q] = rdlane(cA, q); s1v[q] = rdlane(sA, q);
        c2v[q] = rdlane(cB, q); s2v[q] = rdlane(sB, q);
    }
    {
        bool b = m & 1;
        float tr = b ? s1v[0] : c1v[0];
        re = tr * c2v[0];
        im = (b ? tr : -tr) * s2v[0];
    }
    #pragma unroll
    for (int q = 1; q < 4; ++q){
        bool b = (m >> q) & 1;
        float tr = b ? s1v[q] : c1v[q];
        float fre = tr * c2v[q];
        float fim = (b ? tr : -tr) * s2v[q];
        float nre = re*fre - im*fim;
        float nim = re*fim + im*fre;
        re = nre; im = nim;
    }
}

__global__ void __launch_bounds__(256, 4) qlstm_kernel(
    const float* __restrict__ x, const float* __restrict__ phi,
    const float* __restrict__ Wd, const float* __restrict__ bd,
    float* __restrict__ out, int B)
{
    // gtab2[(((k*2+b)*2+l)*4+i)*4 ..+3] = {Ar,Ai,Br,Bi}: merged U=RZ*RY*RX, A=U[b][b], B=U[b][1-b]
    __shared__ __align__(16) float gtab2[384];
    if (threadIdx.x < 96){
        int idx = threadIdx.x;
        int i = idx & 3, l = (idx >> 2) & 1, b = (idx >> 3) & 1, k = idx >> 4;
        const float* pp = phi + (k*2 + l)*12 + 3*i;
        float ca, sa, cb, sb, cg, sg;
        __sincosf(0.5f*pp[0], &sa, &ca);
        __sincosf(0.5f*pp[1], &sb, &cb);
        __sincosf(0.5f*pp[2], &sg, &cg);
        float Ar, Ai, Br, Bi;
        if (b == 0){
            float m00r = cb*ca, m00i = sb*sa;        // row0 of RY*RX
            float m01r = -sb*ca, m01i = -cb*sa;
            Ar = m00r*cg + m00i*sg;  Ai = m00i*cg - m00r*sg;   // * e^{-ig/2}
            Br = m01r*cg + m01i*sg;  Bi = m01i*cg - m01r*sg;
        } else {
            float m10r = sb*ca, m10i = -cb*sa;       // row1 of RY*RX
            float m11r = cb*ca, m11i = -sb*sa;
            Ar = m11r*cg - m11i*sg;  Ai = m11i*cg + m11r*sg;   // * e^{+ig/2}
            Br = m10r*cg - m10i*sg;  Bi = m10i*cg + m10r*sg;
        }
        float* dst = gtab2 + idx*4;
        dst[0] = Ar; dst[1] = Ai; dst[2] = Br; dst[3] = Bi;
    }
    __syncthreads();

    const int lane = threadIdx.x & 63;
    const int b = blockIdx.x * 4 + (threadIdx.x >> 6);   // wave = batch element
    const int m = lane & 15;
    const int grp = lane >> 4;                           // circuit 0..3 (f,i,Cg,o)
    const int k2 = 4 + (grp & 1);                        // phase 2: phi[4]/phi[5]

    // per-lane coefficient addresses: byte off = (k*2+bit_i)*128 + i*16 (+ l*64 at use)
    int a10 = (grp*2 + ((m >> 0) & 1))*128 + 0*16;
    int a11 = (grp*2 + ((m >> 1) & 1))*128 + 1*16;
    int a12 = (grp*2 + ((m >> 2) & 1))*128 + 2*16;
    int a13 = (grp*2 + ((m >> 3) & 1))*128 + 3*16;
    int a20 = (k2*2  + ((m >> 0) & 1))*128 + 0*16;
    int a21 = (k2*2  + ((m >> 1) & 1))*128 + 1*16;
    int a22 = (k2*2  + ((m >> 2) & 1))*128 + 2*16;
    int a23 = (k2*2  + ((m >> 3) & 1))*128 + 3*16;

    // hoisted Wd rows: lane m carries feature m (cols 0..3) + h_m row for m<4
    float wA0 = Wd[m*20+0], wA1 = Wd[m*20+1], wA2 = Wd[m*20+2], wA3 = Wd[m*20+3];
    float wB0 = 0.f, wB1 = 0.f, wB2 = 0.f, wB3 = 0.f;
    if (m < 4){
        wB0 = Wd[(16+m)*20+0]; wB1 = Wd[(16+m)*20+1];
        wB2 = Wd[(16+m)*20+2]; wB3 = Wd[(16+m)*20+3];
    }
    const int q3 = m & 3;
    const float bdsel = bd[q3];

    float h0 = 0.f, h1 = 0.f, h2 = 0.f, h3 = 0.f;
    float cc0 = 0.f, cc1 = 0.f, cc2 = 0.f, cc3 = 0.f;

    const float* xp = x + (size_t)b * TSTEPS * NFEAT;
    float* yp = out + (size_t)b * TSTEPS * 4;

    const bool bb0 = m & 1, bb1 = m & 2;
    float xv = xp[m];
    for (int t = 0; t < TSTEPS; ++t){
        // ---- z (only 4 cols needed): packed butterfly -> lane holds z[m&3]
        float hsel = (m==0)?h0:(m==1)?h1:(m==2)?h2:h3;
        float p0 = xv*wA0 + hsel*wB0;
        float p1 = xv*wA1 + hsel*wB1;
        float p2 = xv*wA2 + hsel*wB2;
        float p3 = xv*wA3 + hsel*wB3;
        float rA = bb0 ? p1 : p0, sA0 = bb0 ? p0 : p1;
        rA += dpp_xor1(sA0);
        float rB = bb0 ? p3 : p2, sB0 = bb0 ? p2 : p3;
        rB += dpp_xor1(sB0);
        float u2 = bb1 ? rB : rA, v2 = bb1 ? rA : rB;
        u2 += dpp_xor2(v2);
        u2 += swz_xor4(u2);
        u2 += swz_xor8(u2);
        float zsel = u2 + bdsel;
        if (t + 1 < TSTEPS) xv = xp[(t+1)*NFEAT + m];

        // ---- Xf = 2*sigmoid(z)-1, packed half-angles (1x instead of 4x), broadcast
        float usel = 1.f - 2.f*frcp(__expf(zsel) + 1.f);
        float cA, sAh, cB, sBh;
        half_cs(usel, cA, sAh);
        half_cs(usel*usel, cB, sBh);
        float re, im;
        build_init(cA, sAh, cB, sBh, m, re, im);

        // ---- phase 1: 4 gate circuits across the 4 groups
        float w1 = circuit(re, im, gtab2, a10, a11, a12, a13, m);
        float w1s = sigm(w1);   // sigmoid the whole vector, then gather
        float fv0=rdlane(w1s, 1), fv1=rdlane(w1s, 2), fv2=rdlane(w1s, 4), fv3=rdlane(w1s, 8);
        float iv0=rdlane(w1s,17), iv1=rdlane(w1s,18), iv2=rdlane(w1s,20), iv3=rdlane(w1s,24);
        float Cv0=rdlane(w1s,33), Cv1=rdlane(w1s,34), Cv2=rdlane(w1s,36), Cv3=rdlane(w1s,40);
        float ov0=rdlane(w1s,49), ov1=rdlane(w1s,50), ov2=rdlane(w1s,52), ov3=rdlane(w1s,56);

        cc0 = fv0*cc0 + iv0*Cv0;
        cc1 = fv1*cc1 + iv1*Cv1;
        cc2 = fv2*cc2 + iv2*Cv2;
        cc3 = fv3*cc3 + iv3*Cv3;

        // packed o*tanh(c) and half-angles (1x instead of 4x)
        float ccsel = (q3==0)?cc0:(q3==1)?cc1:(q3==2)?cc2:cc3;
        float ovsel = (q3==0)?ov0:(q3==1)?ov1:(q3==2)?ov2:ov3;
        float rssel = ovsel * tanh_f(ccsel);
        half_cs(rssel, cA, sAh);
        half_cs(rssel*rssel, cB, sBh);
        float re2, im2;
        build_init(cA, sAh, cB, sBh, m, re2, im2);

        // ---- phase 2: h (group 0, phi[4]) and y (group 1, phi[5])
        float w2 = circuit(re2, im2, gtab2, a20, a21, a22, a23, m);
        h0 = rdlane(w2, 1); h1 = rdlane(w2, 2); h2 = rdlane(w2, 4); h3 = rdlane(w2, 8);
        float y0 = rdlane(w2,17), y1 = rdlane(w2,18), y2 = rdlane(w2,20), y3 = rdlane(w2,24);
        if (lane < 4){
            float yv = (lane==0)?y0:(lane==1)?y1:(lane==2)?y2:y3;
            yp[t*4 + lane] = yv;
        }
    }
    if (lane < 4){
        float* cp = out + (size_t)B*TSTEPS*4 + (size_t)b*4;
        float* hp = out + (size_t)B*TSTEPS*4 + (size_t)B*4 + (size_t)b*4;
        float cv = (lane==0)?cc0:(lane==1)?cc1:(lane==2)?cc2:cc3;
        float hv = (lane==0)?h0:(lane==1)?h1:(lane==2)?h2:h3;
        cp[lane] = cv;
        hp[lane] = hv;
    }
}

extern "C" void kernel_launch(void* const* d_in, const int* in_sizes, int n_in,
                              void* d_out, int out_size, void* d_ws, size_t ws_size,
                              hipStream_t stream) {
    const float* x   = (const float*)d_in[0];
    const float* phi = (const float*)d_in[1];
    const float* Wd  = (const float*)d_in[2];
    const float* bd  = (const float*)d_in[3];
    float* out = (float*)d_out;
    int B = in_sizes[0] / (TSTEPS * NFEAT);   // 4096
    int blocks = (B + 3) / 4;                 // 4 waves (batch elements) per block
    hipLaunchKernelGGL(qlstm_kernel, dim3(blocks), dim3(256), 0, stream,
                       x, phi, Wd, bd, out, B);
}